// Round 6
// baseline (564.133 us; speedup 1.0000x reference)
//
#include <hip/hip_runtime.h>
#include <hip/hip_bf16.h>

typedef unsigned short u16;
typedef __attribute__((ext_vector_type(8))) short short8;
typedef __attribute__((ext_vector_type(4))) float floatx4;

// ---- problem constants ----
#define BB 64
#define SS 192
#define DD 768
#define HH 3072
#define EE 6
#define PP 256
#define SHARED_N 512
#define M_TOT (BB * SS)          // 12288

#define GLD16(gp, lp) __builtin_amdgcn_global_load_lds(                         \
    (const __attribute__((address_space(1))) unsigned int*)(gp),                \
    (__attribute__((address_space(3))) unsigned int*)(lp), 16, 0, 0)

__device__ __forceinline__ u16 f2b(float x) {
  union { float f; unsigned u; } c; c.f = x;
  return (u16)((c.u + 0x7fffu + ((c.u >> 16) & 1u)) >> 16);  // RTNE
}

// tanh-form GELU via sigmoid identity: 0.5x(1+tanh(z)) == x*sigmoid(2z).
__device__ __forceinline__ float fast_gelu(float x) {
  const float c = 2.0f * 0.7978845608028654f * 1.4426950408889634f; // 2*sqrt(2/pi)*log2(e)
  float xp = __builtin_fmaf(0.044715f * x * x, x, x);
  float e = __builtin_amdgcn_exp2f(-c * xp);
  return x * __builtin_amdgcn_rcpf(1.0f + e);
}

#define N_X  9437184L   // 12288*768
#define N_W1 2359296L   // 3072*768
#define N_W2 1572864L   // 512*3072
#define N_WE 4718592L   // 6*256*3072
#define N_ALL (N_X + N_W1 + N_W2 + N_WE)  // 18087936

#define GRID_F 768       // 3 blocks/CU exactly; LDS(33792)->4/CU, VGPR<=128->4/CU
#define EPI_STRIDE 132   // 128+4: 264B row stride spreads q-groups across banks

// ---- software grid barrier (graph-capturable; replaces cg::grid.sync) ----
// Zero-initialized at module load. Generation-based: survives graph replays
// (g_flag monotonically increments; g_cnt returns to 0 after each barrier).
// Residency: grid=768 = 3 blocks/CU with 4/CU capacity -> all co-resident.
// Timeout (~60ms) converts a broken barrier into a visible absmax failure
// instead of a container hang.
__device__ unsigned g_cnt;
__device__ unsigned g_flag;

__device__ __forceinline__ void grid_barrier() {
  __syncthreads();
  if (threadIdx.x == 0) {
    __threadfence();   // agent fence: L2 writeback -> prior writes device-visible
    unsigned old = __hip_atomic_load(&g_flag, __ATOMIC_RELAXED, __HIP_MEMORY_SCOPE_AGENT);
    unsigned arrived = __hip_atomic_fetch_add(&g_cnt, 1u, __ATOMIC_ACQ_REL, __HIP_MEMORY_SCOPE_AGENT);
    if (arrived == GRID_F - 1) {
      __hip_atomic_store(&g_cnt, 0u, __ATOMIC_RELAXED, __HIP_MEMORY_SCOPE_AGENT);
      __hip_atomic_fetch_add(&g_flag, 1u, __ATOMIC_RELEASE, __HIP_MEMORY_SCOPE_AGENT);
    } else {
      unsigned it = 0;
      while (__hip_atomic_load(&g_flag, __ATOMIC_ACQUIRE, __HIP_MEMORY_SCOPE_AGENT) == old) {
        __builtin_amdgcn_s_sleep(2);
        if (++it > (1u << 20)) break;   // ~60ms escape hatch
      }
    }
    __threadfence();   // acquire side: invalidate stale L1/L2 lines
  }
  __syncthreads();
}

// ---------------- fused: cvt -> gbar -> gemm1 -> gbar -> gemm2 -------------
// Phase bodies are the VALIDATED R4 kernels verbatim; only the launch
// structure changes (3 dispatches -> 1) to measure/remove the ~90us
// inter-dispatch overhead (kernel-sum ~160us vs 249.5us total in R0/R4).
__global__ __launch_bounds__(256, 4) void fused_kernel(
    const float* __restrict__ x,  const int* __restrict__ idx,
    const float* __restrict__ w1, const float* __restrict__ b1,
    const float* __restrict__ w2, const float* __restrict__ b2,
    const float* __restrict__ we, const float* __restrict__ be,
    float* __restrict__ out, void* __restrict__ ws) {
  u16* Xb  = (u16*)ws;            // contiguous: Xb | W1b | W2b | WEb | Hb
  u16* W1b = Xb  + N_X;
  u16* W2b = W1b + N_W1;
  u16* WEb = W2b + N_W2;
  u16* Hb  = WEb + N_WE;

  __shared__ u16 smem[128 * EPI_STRIDE];   // 33792 B (all phases reuse it)

  const int tid = threadIdx.x;
  const int lane = tid & 63;
  const int wave = tid >> 6;
  const int q = lane >> 4;
  const int r = lane & 15;
  const int xr = r & 7;

  // ================= phase 0: fp32 -> bf16 conversion ====================
  {
    const long TOT = N_ALL / 8;   // 2260992 vector-tasks of 8 elems
    for (long v = (long)blockIdx.x * 256 + tid; v < TOT; v += (long)GRID_F * 256) {
      long i = v * 8;
      const float* src;
      if (i < N_X)                    src = x  + i;
      else if (i < N_X + N_W1)        src = w1 + (i - N_X);
      else if (i < N_X + N_W1 + N_W2) src = w2 + (i - N_X - N_W1);
      else                            src = we + (i - N_X - N_W1 - N_W2);
      float4 a = *(const float4*)(src);
      float4 b = *(const float4*)(src + 4);
      union { u16 us[8]; uint4 vv; } rr;
      rr.us[0] = f2b(a.x); rr.us[1] = f2b(a.y); rr.us[2] = f2b(a.z); rr.us[3] = f2b(a.w);
      rr.us[4] = f2b(b.x); rr.us[5] = f2b(b.y); rr.us[6] = f2b(b.z); rr.us[7] = f2b(b.w);
      *(uint4*)(Xb + i) = rr.vv;    // Xb..WEb contiguous, same order as ranges
    }
  }
  grid_barrier();

  // ================= phase 1: h = gelu(X @ W1^T + b1) ====================
  // 2304 tiles of 128x128; block b does tiles b, b+768, b+1536 (same m-panel:
  // 768 = 8*96 keeps m0 constant per block -> X rows stay L2-warm).
  {
    u16* As = smem;            // 128*64 u16
    u16* Bs = smem + 8192;     // 128*64 u16
    const int wm = (wave >> 1) * 64;
    const int wn = (wave & 1) * 64;

    int rowc[4], kcg[4];
#pragma unroll
    for (int i = 0; i < 4; ++i) {
      int c = i * 256 + tid;
      rowc[i] = c >> 3;
      kcg[i] = (c & 7) ^ (rowc[i] & 7);
    }

    for (int t = blockIdx.x; t < (M_TOT / 128) * (HH / 128); t += GRID_F) {
      const int m0 = (t % (M_TOT / 128)) * 128;
      const int n0 = (t / (M_TOT / 128)) * 128;
      __syncthreads();   // smem reuse guard across consecutive tiles

      floatx4 acc[4][4] = {};

      for (int kt = 0; kt < DD / 64; ++kt) {
        const int k0 = kt * 64;
#pragma unroll
        for (int i = 0; i < 4; ++i)
          GLD16(Xb + (long)(m0 + rowc[i]) * DD + k0 + kcg[i] * 8, &As[(i * 256 + tid) * 8]);
#pragma unroll
        for (int i = 0; i < 4; ++i)
          GLD16(W1b + (long)(n0 + rowc[i]) * DD + k0 + kcg[i] * 8, &Bs[(i * 256 + tid) * 8]);
        __syncthreads();

#pragma unroll
        for (int ks = 0; ks < 2; ++ks) {
          const int kc = ks * 4 + q;
          short8 a[4], b[4];
#pragma unroll
          for (int i = 0; i < 4; ++i)
            a[i] = *(const short8*)&As[(((wm + i * 16 + r) << 3) + (kc ^ xr)) << 3];
#pragma unroll
          for (int j = 0; j < 4; ++j)
            b[j] = *(const short8*)&Bs[(((wn + j * 16 + r) << 3) + (kc ^ xr)) << 3];
#pragma unroll
          for (int i = 0; i < 4; ++i)
#pragma unroll
            for (int j = 0; j < 4; ++j)
              acc[i][j] = __builtin_amdgcn_mfma_f32_16x16x32_bf16(a[i], b[j], acc[i][j], 0, 0, 0);
        }
        __syncthreads();
      }

      // epilogue: gelu+bias -> bf16 via LDS, coalesced dwordx4 stores
#pragma unroll
      for (int j = 0; j < 4; ++j) {
        const int cl = wn + j * 16 + r;
        const float bn = b1[n0 + cl];
#pragma unroll
        for (int i = 0; i < 4; ++i) {
#pragma unroll
          for (int e = 0; e < 4; ++e) {
            const int rl = wm + i * 16 + q * 4 + e;
            smem[rl * EPI_STRIDE + cl] = f2b(fast_gelu(acc[i][j][e] + bn));
          }
        }
      }
      __syncthreads();

      const int er = tid >> 4;            // 0..15
      const int ec = (tid & 15) * 8;      // 0..120
#pragma unroll
      for (int it = 0; it < 8; ++it) {
        const int rl = er + it * 16;
        uint4 v = *(const uint4*)&smem[rl * EPI_STRIDE + ec];
        *(uint4*)&Hb[(long)(m0 + rl) * HH + n0 + ec] = v;
      }
    }
  }
  grid_barrier();

  // ================= phase 2: out = h @ Wrow^T + bias ====================
  // 768 tiles (128 m-tiles x 6 n-tiles), exactly one per block; index math
  // identical to validated R4 gemm2.
  {
    u16* As = smem;             // 96*64 u16
    u16* Bs = smem + 96 * 64;   // 128*64 u16 (total 28672 B <= 33792)
    const int t = blockIdx.x;
    const int mt = t % (M_TOT / 96);     // 0..127
    const int m0 = mt * 96;
    const int n0 = (t / (M_TOT / 96)) * 128;
    const int wm = (wave >> 1) * 48;
    const int wn = (wave & 1) * 64;

    const u16* Bbase;
    const float* biasp;
    if (n0 < SHARED_N) {
      Bbase = W2b + (long)n0 * HH;
      biasp = b2 + n0;
    } else {
      const int e = idx[mt >> 1];
      Bbase = WEb + ((long)e * PP + (n0 - SHARED_N)) * HH;
      biasp = be + e * PP + (n0 - SHARED_N);
    }
    const u16* Abase = Hb + (long)m0 * HH;

    floatx4 acc[3][4] = {};

    int a_row[3], a_kcg[3], b_row[4], b_kcg[4];
#pragma unroll
    for (int i = 0; i < 3; ++i) {
      int c = i * 256 + tid;
      a_row[i] = c >> 3;
      a_kcg[i] = (c & 7) ^ (a_row[i] & 7);
    }
#pragma unroll
    for (int i = 0; i < 4; ++i) {
      int c = i * 256 + tid;
      b_row[i] = c >> 3;
      b_kcg[i] = (c & 7) ^ (b_row[i] & 7);
    }

    for (int kt = 0; kt < HH / 64; ++kt) {
      const int k0 = kt * 64;
#pragma unroll
      for (int i = 0; i < 3; ++i)
        GLD16(Abase + (long)a_row[i] * HH + k0 + a_kcg[i] * 8, &As[(i * 256 + tid) * 8]);
#pragma unroll
      for (int i = 0; i < 4; ++i)
        GLD16(Bbase + (long)b_row[i] * HH + k0 + b_kcg[i] * 8, &Bs[(i * 256 + tid) * 8]);
      __syncthreads();

      short8 a[2][3], b[2][4];
#pragma unroll
      for (int ks = 0; ks < 2; ++ks) {
        const int kc = ks * 4 + q;
#pragma unroll
        for (int i = 0; i < 3; ++i)
          a[ks][i] = *(const short8*)&As[(((wm + i * 16 + r) << 3) + (kc ^ xr)) << 3];
#pragma unroll
        for (int j = 0; j < 4; ++j)
          b[ks][j] = *(const short8*)&Bs[(((wn + j * 16 + r) << 3) + (kc ^ xr)) << 3];
      }
#pragma unroll
      for (int ks = 0; ks < 2; ++ks)
#pragma unroll
        for (int i = 0; i < 3; ++i)
#pragma unroll
          for (int j = 0; j < 4; ++j)
            acc[i][j] = __builtin_amdgcn_mfma_f32_16x16x32_bf16(a[ks][i], b[ks][j], acc[i][j], 0, 0, 0);
      __syncthreads();
    }

#pragma unroll
    for (int j = 0; j < 4; ++j) {
      const int cl = wn + j * 16 + r;
      const int col = n0 + cl;
      const float bn = biasp[cl];
#pragma unroll
      for (int i = 0; i < 3; ++i) {
#pragma unroll
        for (int e = 0; e < 4; ++e) {
          const int row = m0 + wm + i * 16 + q * 4 + e;
          out[(long)row * DD + col] = acc[i][j][e] + bn;
        }
      }
    }
  }
}

extern "C" void kernel_launch(void* const* d_in, const int* in_sizes, int n_in,
                              void* d_out, int out_size, void* d_ws, size_t ws_size,
                              hipStream_t stream) {
  const float* x  = (const float*)d_in[0];   // [B,S,D]
  const int*  idx = (const int*)d_in[1];     // [B]
  const float* w1 = (const float*)d_in[2];   // [H,D]
  const float* b1 = (const float*)d_in[3];   // [H]
  const float* w2 = (const float*)d_in[4];   // [SHARED,H]
  const float* b2 = (const float*)d_in[5];   // [SHARED]
  const float* we = (const float*)d_in[6];   // [E,P,H]
  const float* be = (const float*)d_in[7];   // [E,P]
  float* out = (float*)d_out;

  fused_kernel<<<dim3(GRID_F), dim3(256), 0, stream>>>(
      x, idx, w1, b1, w2, b2, we, be, out, d_ws);
}

// Round 7
// 245.894 us; speedup vs baseline: 2.2942x; 2.2942x over previous
//
#include <hip/hip_runtime.h>
#include <hip/hip_bf16.h>

typedef unsigned short u16;
typedef __attribute__((ext_vector_type(8))) short short8;
typedef __attribute__((ext_vector_type(4))) float floatx4;

// ---- problem constants ----
#define BB 64
#define SS 192
#define DD 768
#define HH 3072
#define EE 6
#define PP 256
#define SHARED_N 512
#define M_TOT (BB * SS)          // 12288

#define GLD16(gp, lp) __builtin_amdgcn_global_load_lds(                         \
    (const __attribute__((address_space(1))) unsigned int*)(gp),                \
    (__attribute__((address_space(3))) unsigned int*)(lp), 16, 0, 0)

__device__ __forceinline__ u16 f2b(float x) {
  union { float f; unsigned u; } c; c.f = x;
  return (u16)((c.u + 0x7fffu + ((c.u >> 16) & 1u)) >> 16);  // RTNE
}

// tanh-form GELU via sigmoid identity: 0.5x(1+tanh(z)) == x*sigmoid(2z).
// exp2/rcp are single-inst HW approx. Max abs error vs exact-erf GELU ~3e-4,
// far below bf16 rounding of h (~2e-3) and the 3.9e-2 output threshold.
__device__ __forceinline__ float fast_gelu(float x) {
  const float c = 2.0f * 0.7978845608028654f * 1.4426950408889634f; // 2*sqrt(2/pi)*log2(e)
  float xp = __builtin_fmaf(0.044715f * x * x, x, x);
  float e = __builtin_amdgcn_exp2f(-c * xp);
  return x * __builtin_amdgcn_rcpf(1.0f + e);
}

// -------- fp32 -> bf16 conversion, all 4 operands in ONE launch --------
// R7: grid-stride with 2048 blocks (G11) instead of 8832 one-shot blocks.
#define N_X  9437184L   // 12288*768
#define N_W1 2359296L   // 3072*768
#define N_W2 1572864L   // 512*3072
#define N_WE 4718592L   // 6*256*3072
#define N_ALL (N_X + N_W1 + N_W2 + N_WE)  // 18087936
#define CVT_GRID 2048

__global__ __launch_bounds__(256) void cvt_all_kernel(const float* __restrict__ x,
                                                      const float* __restrict__ w1,
                                                      const float* __restrict__ w2,
                                                      const float* __restrict__ we,
                                                      u16* __restrict__ dst) {
  const long TOT = N_ALL / 8;
  for (long v = (long)blockIdx.x * 256 + threadIdx.x; v < TOT; v += (long)CVT_GRID * 256) {
    long i = v * 8;
    const float* src;
    if (i < N_X)                    src = x  + i;
    else if (i < N_X + N_W1)        src = w1 + (i - N_X);
    else if (i < N_X + N_W1 + N_W2) src = w2 + (i - N_X - N_W1);
    else                            src = we + (i - N_X - N_W1 - N_W2);
    float4 a = *(const float4*)(src);
    float4 b = *(const float4*)(src + 4);
    union { u16 us[8]; uint4 v4; } r;
    r.us[0] = f2b(a.x); r.us[1] = f2b(a.y); r.us[2] = f2b(a.z); r.us[3] = f2b(a.w);
    r.us[4] = f2b(b.x); r.us[5] = f2b(b.y); r.us[6] = f2b(b.z); r.us[7] = f2b(b.w);
    *(uint4*)(dst + i) = r.v4;
  }
}

// ---------------- GEMM1: h = gelu(X @ W1^T + b1), bf16 out ----------------
// 128x128 tile, BK=64, XOR-swizzled LDS (validated structure, 69.0us).
#define EPI_STRIDE 132   // 128+4: 264B row stride spreads q-groups across banks
__global__ __launch_bounds__(256, 4) void gemm1_kernel(const u16* __restrict__ X,
                                                       const u16* __restrict__ W,
                                                       const float* __restrict__ bias,
                                                       u16* __restrict__ H) {
  constexpr int K = DD;      // 768
  constexpr int N = HH;      // 3072
  __shared__ u16 smem[128 * EPI_STRIDE];   // 33792 B; K-loop uses first 32 KB
  u16* As = smem;            // 128*64
  u16* Bs = smem + 8192;     // 128*64
  const int tid = threadIdx.x;
  const int lane = tid & 63;
  const int wave = tid >> 6;
  const int m0 = blockIdx.x * 128;
  const int n0 = blockIdx.y * 128;
  const int wm = (wave >> 1) * 64;
  const int wn = (wave & 1) * 64;
  const int q = lane >> 4;
  const int r = lane & 15;
  const int xr = r & 7;

  floatx4 acc[4][4] = {};

  // staging chunk assignments: 128 rows x 8 chunks(16B) = 1024 chunks, 4/thread
  int rowc[4], kcg[4];
#pragma unroll
  for (int i = 0; i < 4; ++i) {
    int c = i * 256 + tid;
    rowc[i] = c >> 3;
    kcg[i] = (c & 7) ^ (rowc[i] & 7);
  }

  for (int kt = 0; kt < K / 64; ++kt) {
    const int k0 = kt * 64;
#pragma unroll
    for (int i = 0; i < 4; ++i)
      GLD16(X + (long)(m0 + rowc[i]) * K + k0 + kcg[i] * 8, &As[(i * 256 + tid) * 8]);
#pragma unroll
    for (int i = 0; i < 4; ++i)
      GLD16(W + (long)(n0 + rowc[i]) * K + k0 + kcg[i] * 8, &Bs[(i * 256 + tid) * 8]);
    __syncthreads();

#pragma unroll
    for (int ks = 0; ks < 2; ++ks) {
      const int kc = ks * 4 + q;
      short8 a[4], b[4];
#pragma unroll
      for (int i = 0; i < 4; ++i)
        a[i] = *(const short8*)&As[(((wm + i * 16 + r) << 3) + (kc ^ xr)) << 3];
#pragma unroll
      for (int j = 0; j < 4; ++j)
        b[j] = *(const short8*)&Bs[(((wn + j * 16 + r) << 3) + (kc ^ xr)) << 3];
#pragma unroll
      for (int i = 0; i < 4; ++i)
#pragma unroll
        for (int j = 0; j < 4; ++j)
          acc[i][j] = __builtin_amdgcn_mfma_f32_16x16x32_bf16(a[i], b[j], acc[i][j], 0, 0, 0);
    }
    __syncthreads();
  }
  // last loop barrier guarantees all frag reads done -> smem reusable

#pragma unroll
  for (int j = 0; j < 4; ++j) {
    const int cl = wn + j * 16 + r;
    const float bn = bias[n0 + cl];
#pragma unroll
    for (int i = 0; i < 4; ++i) {
#pragma unroll
      for (int e = 0; e < 4; ++e) {
        const int rl = wm + i * 16 + q * 4 + e;
        smem[rl * EPI_STRIDE + cl] = f2b(fast_gelu(acc[i][j][e] + bn));
      }
    }
  }
  __syncthreads();

  const int er = tid >> 4;            // 0..15
  const int ec = (tid & 15) * 8;      // 0..120
#pragma unroll
  for (int it = 0; it < 8; ++it) {
    const int rl = er + it * 16;
    uint4 v = *(const uint4*)&smem[rl * EPI_STRIDE + ec];
    *(uint4*)&H[(long)(m0 + rl) * N + n0 + ec] = v;
  }
}

// ---------------- GEMM2: out = h @ Wrow^T + bias, fp32 out ----------------
// BM=96 (one batch per row-tile), BN=128, BK=64, XOR-swizzled LDS.
// Grid = 128 x 6 = 768 blocks = exactly 3/CU, perfectly balanced.
__global__ __launch_bounds__(256, 4) void gemm2_kernel(const u16* __restrict__ Hb,
                                                       const u16* __restrict__ W2,
                                                       const u16* __restrict__ WE,
                                                       const float* __restrict__ b2,
                                                       const float* __restrict__ be,
                                                       const int* __restrict__ idx,
                                                       float* __restrict__ Out) {
  constexpr int K = HH;       // 3072
  constexpr int NOUT = DD;    // 768
  __shared__ u16 As[96 * 64];    // 12 KB
  __shared__ u16 Bs[128 * 64];   // 16 KB
  const int tid = threadIdx.x;
  const int lane = tid & 63;
  const int wave = tid >> 6;
  const int m0 = blockIdx.x * 96;
  const int n0 = blockIdx.y * 128;
  const int wm = (wave >> 1) * 48;
  const int wn = (wave & 1) * 64;
  const int q = lane >> 4;
  const int r = lane & 15;
  const int xr = r & 7;

  const u16* Bbase;
  const float* biasp;
  if (n0 < SHARED_N) {
    Bbase = W2 + (long)n0 * K;
    biasp = b2 + n0;
  } else {
    const int e = idx[blockIdx.x >> 1];
    Bbase = WE + ((long)e * PP + (n0 - SHARED_N)) * K;
    biasp = be + e * PP + (n0 - SHARED_N);
  }
  const u16* Abase = Hb + (long)m0 * K;

  floatx4 acc[3][4] = {};

  int a_row[3], a_kcg[3], b_row[4], b_kcg[4];
#pragma unroll
  for (int i = 0; i < 3; ++i) {
    int c = i * 256 + tid;
    a_row[i] = c >> 3;
    a_kcg[i] = (c & 7) ^ (a_row[i] & 7);
  }
#pragma unroll
  for (int i = 0; i < 4; ++i) {
    int c = i * 256 + tid;
    b_row[i] = c >> 3;
    b_kcg[i] = (c & 7) ^ (b_row[i] & 7);
  }

  for (int kt = 0; kt < K / 64; ++kt) {
    const int k0 = kt * 64;
#pragma unroll
    for (int i = 0; i < 3; ++i)
      GLD16(Abase + (long)a_row[i] * K + k0 + a_kcg[i] * 8, &As[(i * 256 + tid) * 8]);
#pragma unroll
    for (int i = 0; i < 4; ++i)
      GLD16(Bbase + (long)b_row[i] * K + k0 + b_kcg[i] * 8, &Bs[(i * 256 + tid) * 8]);
    __syncthreads();

    short8 a[2][3], b[2][4];
#pragma unroll
    for (int ks = 0; ks < 2; ++ks) {
      const int kc = ks * 4 + q;
#pragma unroll
      for (int i = 0; i < 3; ++i)
        a[ks][i] = *(const short8*)&As[(((wm + i * 16 + r) << 3) + (kc ^ xr)) << 3];
#pragma unroll
      for (int j = 0; j < 4; ++j)
        b[ks][j] = *(const short8*)&Bs[(((wn + j * 16 + r) << 3) + (kc ^ xr)) << 3];
    }
#pragma unroll
    for (int ks = 0; ks < 2; ++ks)
#pragma unroll
      for (int i = 0; i < 3; ++i)
#pragma unroll
        for (int j = 0; j < 4; ++j)
          acc[i][j] = __builtin_amdgcn_mfma_f32_16x16x32_bf16(a[ks][i], b[ks][j], acc[i][j], 0, 0, 0);
    __syncthreads();
  }

#pragma unroll
  for (int j = 0; j < 4; ++j) {
    const int cl = wn + j * 16 + r;
    const int col = n0 + cl;
    const float bn = biasp[cl];
#pragma unroll
    for (int i = 0; i < 3; ++i) {
#pragma unroll
      for (int e = 0; e < 4; ++e) {
        const int row = m0 + wm + i * 16 + q * 4 + e;
        Out[(long)row * NOUT + col] = acc[i][j][e] + bn;
      }
    }
  }
}

extern "C" void kernel_launch(void* const* d_in, const int* in_sizes, int n_in,
                              void* d_out, int out_size, void* d_ws, size_t ws_size,
                              hipStream_t stream) {
  const float* x  = (const float*)d_in[0];   // [B,S,D]
  const int*  idx = (const int*)d_in[1];     // [B]
  const float* w1 = (const float*)d_in[2];   // [H,D]
  const float* b1 = (const float*)d_in[3];   // [H]
  const float* w2 = (const float*)d_in[4];   // [SHARED,H]
  const float* b2 = (const float*)d_in[5];   // [SHARED]
  const float* we = (const float*)d_in[6];   // [E,P,H]
  const float* be = (const float*)d_in[7];   // [E,P]
  float* out = (float*)d_out;

  u16* Xb  = (u16*)d_ws;                              // 12288*768
  u16* W1b = Xb  + N_X;                               // 3072*768
  u16* W2b = W1b + N_W1;                              // 512*3072
  u16* WEb = W2b + N_W2;                              // 6*256*3072
  u16* Hb  = WEb + N_WE;                              // 12288*3072

  cvt_all_kernel<<<CVT_GRID, 256, 0, stream>>>(x, w1, w2, we, Xb);
  gemm1_kernel<<<dim3(M_TOT / 128, HH / 128), 256, 0, stream>>>(Xb, W1b, b1, Hb);
  gemm2_kernel<<<dim3(M_TOT / 96, DD / 128), 256, 0, stream>>>(Hb, W2b, WEb, b2, be, idx, out);
}